// Round 5
// baseline (71.340 us; speedup 1.0000x reference)
//
#include <hip/hip_runtime.h>
#include <hip/hip_bf16.h>
#include <math.h>

#define B_    4
#define N_    2048
#define INF_  256
#define OUTF_ 64
#define H_    8
#define C_    512   // H_*OUTF_

typedef __attribute__((ext_vector_type(8))) short  bf16x8;
typedef __attribute__((ext_vector_type(4))) short  s16x4;
typedef __attribute__((ext_vector_type(4))) float  f32x4;

static __device__ __forceinline__ short f2b(float f) {
    union { float f; unsigned u; } v; v.f = f;
    unsigned r = (v.u + 0x7FFFu + ((v.u >> 16) & 1u)) >> 16;  // RNE
    return (short)r;
}
static __device__ __forceinline__ float b2f(short s) {
    union { unsigned u; float f; } v; v.u = ((unsigned)(unsigned short)s) << 16;
    return v.f;
}

#define GL2LDS(gsrc, ldst)                                                          \
    __builtin_amdgcn_global_load_lds(                                               \
        (const __attribute__((address_space(1))) void*)(gsrc),                      \
        (__attribute__((address_space(3))) void*)(ldst), 16, 0, 0)

// ---------------------------------------------------------------------------
// Kernel 1: fused casts (one launch).
//   blocks [0,8192):        adj -> adjb (bf16 0/1)
//   blocks [8192,9216):     x   -> xb  (bf16)
//   blocks [9216,9248):     W[256][512] -> wbT[512][256] (bf16 transposed)
// ---------------------------------------------------------------------------
__global__ __launch_bounds__(256)
void cast_kernel(const float* __restrict__ x, const float* __restrict__ w,
                 const int* __restrict__ adj,
                 short* __restrict__ xb, short* __restrict__ wbT,
                 short* __restrict__ adjb) {
    __shared__ short T[64][72];
    const int bid = blockIdx.x;
    if (bid < 8192) {
        size_t i8 = (size_t)bid * 256 + threadIdx.x;
        const int4* p = reinterpret_cast<const int4*>(adj + i8 * 8);
        int4 v0 = p[0], v1 = p[1];
        bf16x8 o;
        o[0] = v0.x ? (short)0x3F80 : (short)0;
        o[1] = v0.y ? (short)0x3F80 : (short)0;
        o[2] = v0.z ? (short)0x3F80 : (short)0;
        o[3] = v0.w ? (short)0x3F80 : (short)0;
        o[4] = v1.x ? (short)0x3F80 : (short)0;
        o[5] = v1.y ? (short)0x3F80 : (short)0;
        o[6] = v1.z ? (short)0x3F80 : (short)0;
        o[7] = v1.w ? (short)0x3F80 : (short)0;
        *reinterpret_cast<bf16x8*>(adjb + i8 * 8) = o;
    } else if (bid < 9216) {
        size_t i8 = (size_t)(bid - 8192) * 256 + threadIdx.x;
        const float4* p = reinterpret_cast<const float4*>(x + i8 * 8);
        float4 v0 = p[0], v1 = p[1];
        bf16x8 o;
        o[0] = f2b(v0.x); o[1] = f2b(v0.y); o[2] = f2b(v0.z); o[3] = f2b(v0.w);
        o[4] = f2b(v1.x); o[5] = f2b(v1.y); o[6] = f2b(v1.z); o[7] = f2b(v1.w);
        *reinterpret_cast<bf16x8*>(xb + i8 * 8) = o;
    } else {
        int blk = bid - 9216;                 // 32 blocks: 8 c-tiles x 4 k-tiles
        int c0 = (blk & 7) * 64;
        int k0 = (blk >> 3) * 64;
        int t = threadIdx.x;
        int cl = (t & 15) * 4;
#pragma unroll
        for (int p = 0; p < 4; ++p) {
            int kl = p * 16 + (t >> 4);
            float4 v = *reinterpret_cast<const float4*>(&w[(size_t)(k0 + kl) * C_ + c0 + cl]);
            T[cl + 0][kl] = f2b(v.x);
            T[cl + 1][kl] = f2b(v.y);
            T[cl + 2][kl] = f2b(v.z);
            T[cl + 3][kl] = f2b(v.w);
        }
        __syncthreads();
        int cr = t >> 2;
        int ks = (t & 3) * 16;
        short* dst = &wbT[(size_t)(c0 + cr) * INF_ + k0 + ks];
        *reinterpret_cast<bf16x8*>(dst)     = *reinterpret_cast<const bf16x8*>(&T[cr][ks]);
        *reinterpret_cast<bf16x8*>(dst + 8) = *reinterpret_cast<const bf16x8*>(&T[cr][ks + 8]);
    }
}

// ---------------------------------------------------------------------------
// Kernel 2: fused projection (bf16 MFMA) + e + gT.
//   h-tile[128 rows][64 cols=one head] = xb @ wbT^T   (regs, fp32 acc)
//   s[j]  = sum_f h[j][f]*attn_dst[head][f]   (shfl + LDS reduce)
//   e     = bf16(exp(s))  -> ebT[b][head][j]
//   g     = bf16(e * h)   -> gT[b][c][j]      (LDS transpose)
// hb is never materialized.
// ---------------------------------------------------------------------------
__global__ __launch_bounds__(256)
void proj_fused(const short* __restrict__ xb, const short* __restrict__ wbT,
                const float* __restrict__ attn_dst,
                short* __restrict__ ebT, short* __restrict__ gT) {
    __shared__ char smem[24576];
    short* As = (short*)smem;                  // 16 KiB  [128][64] swizzled
    short* Bs = (short*)(smem + 16384);        //  8 KiB  [64][64]  swizzled
    // epilogue carve (after final barrier):
    short* Tt = (short*)smem;                  // 64 x 136 bf16 = 17408 B
    float* Sr = (float*)(smem + 17408);        // 2 x 128 f32   = 1024 B
    short* Eb = (short*)(smem + 18432);        // 128 bf16      = 256 B

    const int m0 = blockIdx.x * 128;           // global row (b*N + j)
    const int n0 = blockIdx.y * 64;            // feature col = head*64
    const int head = n0 >> 6;
    const int b    = m0 >> 11;
    const int j0g  = m0 & (N_ - 1);
    const int wid  = threadIdx.x >> 6;
    const int lane = threadIdx.x & 63;
    const int wr = wid >> 1, wc = wid & 1;
    const int q4 = lane >> 4, l15 = lane & 15;
    const int lr = lane >> 3;
    const int ls = (lane & 7) ^ lr;
    const short* Abase = xb + (size_t)m0 * INF_;
    const short* Bbase = wbT + (size_t)n0 * INF_;

    f32x4 acc[4][2];
#pragma unroll
    for (int m = 0; m < 4; ++m)
#pragma unroll
        for (int n = 0; n < 2; ++n) acc[m][n] = (f32x4){0.f, 0.f, 0.f, 0.f};

    for (int k0 = 0; k0 < INF_; k0 += 64) {
#pragma unroll
        for (int q = 0; q < 4; ++q) {
            int chunk = wid * 4 + q;
            int row   = chunk * 8 + lr;
            GL2LDS(Abase + (size_t)row * INF_ + k0 + ls * 8, As + chunk * 512);
        }
#pragma unroll
        for (int q = 0; q < 2; ++q) {
            int chunk = wid * 2 + q;
            int row   = chunk * 8 + lr;
            GL2LDS(Bbase + (size_t)row * INF_ + k0 + ls * 8, Bs + chunk * 512);
        }
        __syncthreads();
#pragma unroll
        for (int kk = 0; kk < 2; ++kk) {
            const int ko = kk * 32 + q4 * 8;
            bf16x8 a[4], bb[2];
#pragma unroll
            for (int m = 0; m < 4; ++m) {
                int row = wr * 64 + m * 16 + l15;
                a[m] = *reinterpret_cast<const bf16x8*>(&As[row * 64 + (ko ^ ((row & 7) * 8))]);
            }
#pragma unroll
            for (int n = 0; n < 2; ++n) {
                int row = wc * 32 + n * 16 + l15;
                bb[n] = *reinterpret_cast<const bf16x8*>(&Bs[row * 64 + (ko ^ ((row & 7) * 8))]);
            }
#pragma unroll
            for (int m = 0; m < 4; ++m)
#pragma unroll
                for (int n = 0; n < 2; ++n)
                    acc[m][n] = __builtin_amdgcn_mfma_f32_16x16x32_bf16(a[m], bb[n], acc[m][n], 0, 0, 0);
        }
        __syncthreads();
    }

    // ---- epilogue: s = h . a  (per-row, fp32) ----
    float af0 = attn_dst[head * 64 + wc * 32 + l15];
    float af1 = attn_dst[head * 64 + wc * 32 + 16 + l15];
#pragma unroll
    for (int m = 0; m < 4; ++m) {
        f32x4 part;
#pragma unroll
        for (int r = 0; r < 4; ++r)
            part[r] = acc[m][0][r] * af0 + acc[m][1][r] * af1;
#pragma unroll
        for (int off = 1; off < 16; off <<= 1)
#pragma unroll
            for (int r = 0; r < 4; ++r) part[r] += __shfl_xor(part[r], off);
        if (l15 == 0)
            *reinterpret_cast<f32x4*>(&Sr[wc * 128 + wr * 64 + m * 16 + q4 * 4]) = part;
    }
    __syncthreads();
    const int t = threadIdx.x;
    if (t < 128) {
        float s = Sr[t] + Sr[128 + t];
        short eb = f2b(expf(s));
        Eb[t] = eb;
        ebT[((size_t)b * H_ + head) * N_ + j0g + t] = eb;
    }
    __syncthreads();
    // ---- g = e*h, transpose to [c][j] ----
#pragma unroll
    for (int m = 0; m < 4; ++m) {
        int jl = wr * 64 + m * 16 + q4 * 4;
        float ev[4];
#pragma unroll
        for (int r = 0; r < 4; ++r) ev[r] = b2f(Eb[jl + r]);
#pragma unroll
        for (int n = 0; n < 2; ++n) {
            int cl = wc * 32 + n * 16 + l15;
            s16x4 gv;
#pragma unroll
            for (int r = 0; r < 4; ++r) gv[r] = f2b(acc[m][n][r] * ev[r]);
            *reinterpret_cast<s16x4*>(&Tt[cl * 136 + jl]) = gv;
        }
    }
    __syncthreads();
    {
        int c  = t >> 2;
        int jc = (t & 3) * 32;
        short* dst = &gT[((size_t)b * C_ + n0 + c) * N_ + j0g + jc];
#pragma unroll
        for (int u = 0; u < 4; ++u)
            *reinterpret_cast<bf16x8*>(dst + u * 8) =
                *reinterpret_cast<const bf16x8*>(&Tt[c * 136 + jc + u * 8]);
    }
}

// ---------------------------------------------------------------------------
// Kernel 3: numerator GEMM (bf16 MFMA) + denominator + divide:
//   num[i,c] = sum_j adjb[b,i,j] * gT[b,c,j]
//   den[i]   = sum_j adjb[b,i,j] * e[b,head,j]  (wc==0 waves only; LDS share)
//   out      = num / den
// BM=128, BN=64, BK=64; head uniform per block.
// ---------------------------------------------------------------------------
__global__ __launch_bounds__(256)
void agg_mfma(const short* __restrict__ adjb, const short* __restrict__ gT,
              const short* __restrict__ ebT, float* __restrict__ out) {
    __shared__ short As[128 * 64];   // 16 KiB
    __shared__ short Bs[64 * 64];    //  8 KiB
    __shared__ short Es[N_];         //  4 KiB : e[b, head, :]
    __shared__ float Dr[128];        // den share
    const int b  = blockIdx.z;
    const int m0 = blockIdx.x * 128;
    const int n0 = blockIdx.y * 64;
    const int head = n0 >> 6;
    const int wid  = threadIdx.x >> 6;
    const int lane = threadIdx.x & 63;
    const int wr = wid >> 1, wc = wid & 1;
    const int q4 = lane >> 4, l15 = lane & 15;
    const int lr = lane >> 3;
    const int ls = (lane & 7) ^ lr;
    const short* Abase = adjb + (size_t)b * N_ * N_ + (size_t)m0 * N_;
    const short* Bbase = gT   + (size_t)b * C_ * N_ + (size_t)n0 * N_;
    const short* Ebase = ebT  + ((size_t)b * H_ + head) * N_;

    GL2LDS(Ebase + wid * 512 + lane * 8, Es + wid * 512);

    f32x4 acc[4][2];
    f32x4 accd[4];
#pragma unroll
    for (int m = 0; m < 4; ++m) {
        accd[m] = (f32x4){0.f, 0.f, 0.f, 0.f};
#pragma unroll
        for (int n = 0; n < 2; ++n) acc[m][n] = (f32x4){0.f, 0.f, 0.f, 0.f};
    }

    for (int k0 = 0; k0 < N_; k0 += 64) {
#pragma unroll
        for (int q = 0; q < 4; ++q) {
            int chunk = wid * 4 + q;
            int row   = chunk * 8 + lr;
            GL2LDS(Abase + (size_t)row * N_ + k0 + ls * 8, As + chunk * 512);
        }
#pragma unroll
        for (int q = 0; q < 2; ++q) {
            int chunk = wid * 2 + q;
            int row   = chunk * 8 + lr;
            GL2LDS(Bbase + (size_t)row * N_ + k0 + ls * 8, Bs + chunk * 512);
        }
        __syncthreads();
#pragma unroll
        for (int kk = 0; kk < 2; ++kk) {
            const int ko = kk * 32 + q4 * 8;
            bf16x8 a[4], bb[2];
#pragma unroll
            for (int m = 0; m < 4; ++m) {
                int row = wr * 64 + m * 16 + l15;
                a[m] = *reinterpret_cast<const bf16x8*>(&As[row * 64 + (ko ^ ((row & 7) * 8))]);
            }
#pragma unroll
            for (int n = 0; n < 2; ++n) {
                int row = wc * 32 + n * 16 + l15;
                bb[n] = *reinterpret_cast<const bf16x8*>(&Bs[row * 64 + (ko ^ ((row & 7) * 8))]);
            }
#pragma unroll
            for (int m = 0; m < 4; ++m)
#pragma unroll
                for (int n = 0; n < 2; ++n)
                    acc[m][n] = __builtin_amdgcn_mfma_f32_16x16x32_bf16(a[m], bb[n], acc[m][n], 0, 0, 0);
            if (wc == 0) {
                bf16x8 be = *reinterpret_cast<const bf16x8*>(&Es[k0 + ko]);
#pragma unroll
                for (int m = 0; m < 4; ++m)
                    accd[m] = __builtin_amdgcn_mfma_f32_16x16x32_bf16(a[m], be, accd[m], 0, 0, 0);
            }
        }
        __syncthreads();
    }
    // den -> LDS (wc==0 holds it; every col of accd equal)
    if (wc == 0) {
#pragma unroll
        for (int m = 0; m < 4; ++m)
            if (l15 == 0)
                *reinterpret_cast<f32x4*>(&Dr[wr * 64 + m * 16 + q4 * 4]) = accd[m];
    }
    __syncthreads();
    float* obase = out + (size_t)b * N_ * C_;
#pragma unroll
    for (int m = 0; m < 4; ++m) {
        int jl = wr * 64 + m * 16 + q4 * 4;
        int gr = m0 + jl;
        float inv[4];
#pragma unroll
        for (int r = 0; r < 4; ++r) inv[r] = 1.0f / Dr[jl + r];
#pragma unroll
        for (int n = 0; n < 2; ++n) {
            int gc = n0 + wc * 32 + n * 16 + l15;
#pragma unroll
            for (int r = 0; r < 4; ++r)
                obase[(size_t)(gr + r) * C_ + gc] = acc[m][n][r] * inv[r];
        }
    }
}

// ---------------------------------------------------------------------------
extern "C" void kernel_launch(void* const* d_in, const int* in_sizes, int n_in,
                              void* d_out, int out_size, void* d_ws, size_t ws_size,
                              hipStream_t stream) {
    const float* x        = (const float*)d_in[0];
    const int*   adj      = (const int*)d_in[1];
    const float* weight   = (const float*)d_in[2];
    // d_in[3] = attn_src : unused (cancels in softmax over neighbors j)
    const float* attn_dst = (const float*)d_in[4];
    float* out = (float*)d_out;

    // workspace:
    //   xb   : 4 MiB bf16
    //   wbT  : 256 KiB bf16
    //   ebT  : 128 KiB bf16   [b][h][j]
    //   adjb : 32 MiB bf16
    //   gT   : 8 MiB bf16     [b][c][j]
    short* xb   = (short*)d_ws;
    short* wbT  = xb + (size_t)B_ * N_ * INF_;
    short* ebT  = wbT + (size_t)C_ * INF_;
    short* adjb = ebT + (size_t)B_ * H_ * N_;
    short* gT   = adjb + (size_t)B_ * N_ * N_;

    // 1. fused casts: adj->adjb, x->xb, W->wbT
    cast_kernel<<<dim3(8192 + 1024 + 32), 256, 0, stream>>>(x, weight, adj, xb, wbT, adjb);
    // 2. fused projection + e + gT
    proj_fused<<<dim3((B_ * N_) / 128, C_ / 64), 256, 0, stream>>>(xb, wbT, attn_dst, ebT, gT);
    // 3. numerator GEMM + denominator (MFMA) + divide -> out
    agg_mfma<<<dim3(N_ / 128, C_ / 64, B_), 256, 0, stream>>>(adjb, gT, ebT, out);
}

// Round 6
// 70.364 us; speedup vs baseline: 1.0139x; 1.0139x over previous
//
#include <hip/hip_runtime.h>
#include <hip/hip_bf16.h>
#include <math.h>

#define B_    4
#define N_    2048
#define INF_  256
#define OUTF_ 64
#define H_    8
#define C_    512   // H_*OUTF_

typedef __attribute__((ext_vector_type(8))) short  bf16x8;
typedef __attribute__((ext_vector_type(4))) short  s16x4;
typedef __attribute__((ext_vector_type(4))) float  f32x4;

static __device__ __forceinline__ short f2b(float f) {
    union { float f; unsigned u; } v; v.f = f;
    unsigned r = (v.u + 0x7FFFu + ((v.u >> 16) & 1u)) >> 16;  // RNE
    return (short)r;
}
static __device__ __forceinline__ float b2f(short s) {
    union { unsigned u; float f; } v; v.u = ((unsigned)(unsigned short)s) << 16;
    return v.f;
}

#define GL2LDS(gsrc, ldst)                                                          \
    __builtin_amdgcn_global_load_lds(                                               \
        (const __attribute__((address_space(1))) void*)(gsrc),                      \
        (__attribute__((address_space(3))) void*)(ldst), 16, 0, 0)

// ---------------------------------------------------------------------------
// Kernel 1: casts. blocks [0,1024): x -> xb (bf16). blocks [1024,1056):
// W[256][512] -> wbT[512][256] (bf16, transposed).  (adj cast eliminated)
// ---------------------------------------------------------------------------
__global__ __launch_bounds__(256)
void cast_kernel(const float* __restrict__ x, const float* __restrict__ w,
                 short* __restrict__ xb, short* __restrict__ wbT) {
    __shared__ short T[64][72];
    const int bid = blockIdx.x;
    if (bid < 1024) {
        size_t i8 = (size_t)bid * 256 + threadIdx.x;
        const float4* p = reinterpret_cast<const float4*>(x + i8 * 8);
        float4 v0 = p[0], v1 = p[1];
        bf16x8 o;
        o[0] = f2b(v0.x); o[1] = f2b(v0.y); o[2] = f2b(v0.z); o[3] = f2b(v0.w);
        o[4] = f2b(v1.x); o[5] = f2b(v1.y); o[6] = f2b(v1.z); o[7] = f2b(v1.w);
        *reinterpret_cast<bf16x8*>(xb + i8 * 8) = o;
    } else {
        int blk = bid - 1024;                 // 32 blocks: 8 c-tiles x 4 k-tiles
        int c0 = (blk & 7) * 64;
        int k0 = (blk >> 3) * 64;
        int t = threadIdx.x;
        int cl = (t & 15) * 4;
#pragma unroll
        for (int p = 0; p < 4; ++p) {
            int kl = p * 16 + (t >> 4);
            float4 v = *reinterpret_cast<const float4*>(&w[(size_t)(k0 + kl) * C_ + c0 + cl]);
            T[cl + 0][kl] = f2b(v.x);
            T[cl + 1][kl] = f2b(v.y);
            T[cl + 2][kl] = f2b(v.z);
            T[cl + 3][kl] = f2b(v.w);
        }
        __syncthreads();
        int cr = t >> 2;
        int ks = (t & 3) * 16;
        short* dst = &wbT[(size_t)(c0 + cr) * INF_ + k0 + ks];
        *reinterpret_cast<bf16x8*>(dst)     = *reinterpret_cast<const bf16x8*>(&T[cr][ks]);
        *reinterpret_cast<bf16x8*>(dst + 8) = *reinterpret_cast<const bf16x8*>(&T[cr][ks + 8]);
    }
}

// ---------------------------------------------------------------------------
// Kernel 2: fused projection (bf16 MFMA) + e + gT.  (unchanged, validated)
// ---------------------------------------------------------------------------
__global__ __launch_bounds__(256)
void proj_fused(const short* __restrict__ xb, const short* __restrict__ wbT,
                const float* __restrict__ attn_dst,
                short* __restrict__ ebT, short* __restrict__ gT) {
    __shared__ char smem[24576];
    short* As = (short*)smem;                  // 16 KiB  [128][64] swizzled
    short* Bs = (short*)(smem + 16384);        //  8 KiB  [64][64]  swizzled
    short* Tt = (short*)smem;                  // 64 x 136 bf16 = 17408 B
    float* Sr = (float*)(smem + 17408);        // 2 x 128 f32   = 1024 B
    short* Eb = (short*)(smem + 18432);        // 128 bf16      = 256 B

    const int m0 = blockIdx.x * 128;
    const int n0 = blockIdx.y * 64;
    const int head = n0 >> 6;
    const int b    = m0 >> 11;
    const int j0g  = m0 & (N_ - 1);
    const int wid  = threadIdx.x >> 6;
    const int lane = threadIdx.x & 63;
    const int wr = wid >> 1, wc = wid & 1;
    const int q4 = lane >> 4, l15 = lane & 15;
    const int lr = lane >> 3;
    const int ls = (lane & 7) ^ lr;
    const short* Abase = xb + (size_t)m0 * INF_;
    const short* Bbase = wbT + (size_t)n0 * INF_;

    f32x4 acc[4][2];
#pragma unroll
    for (int m = 0; m < 4; ++m)
#pragma unroll
        for (int n = 0; n < 2; ++n) acc[m][n] = (f32x4){0.f, 0.f, 0.f, 0.f};

    for (int k0 = 0; k0 < INF_; k0 += 64) {
#pragma unroll
        for (int q = 0; q < 4; ++q) {
            int chunk = wid * 4 + q;
            int row   = chunk * 8 + lr;
            GL2LDS(Abase + (size_t)row * INF_ + k0 + ls * 8, As + chunk * 512);
        }
#pragma unroll
        for (int q = 0; q < 2; ++q) {
            int chunk = wid * 2 + q;
            int row   = chunk * 8 + lr;
            GL2LDS(Bbase + (size_t)row * INF_ + k0 + ls * 8, Bs + chunk * 512);
        }
        __syncthreads();
#pragma unroll
        for (int kk = 0; kk < 2; ++kk) {
            const int ko = kk * 32 + q4 * 8;
            bf16x8 a[4], bb[2];
#pragma unroll
            for (int m = 0; m < 4; ++m) {
                int row = wr * 64 + m * 16 + l15;
                a[m] = *reinterpret_cast<const bf16x8*>(&As[row * 64 + (ko ^ ((row & 7) * 8))]);
            }
#pragma unroll
            for (int n = 0; n < 2; ++n) {
                int row = wc * 32 + n * 16 + l15;
                bb[n] = *reinterpret_cast<const bf16x8*>(&Bs[row * 64 + (ko ^ ((row & 7) * 8))]);
            }
#pragma unroll
            for (int m = 0; m < 4; ++m)
#pragma unroll
                for (int n = 0; n < 2; ++n)
                    acc[m][n] = __builtin_amdgcn_mfma_f32_16x16x32_bf16(a[m], bb[n], acc[m][n], 0, 0, 0);
        }
        __syncthreads();
    }

    float af0 = attn_dst[head * 64 + wc * 32 + l15];
    float af1 = attn_dst[head * 64 + wc * 32 + 16 + l15];
#pragma unroll
    for (int m = 0; m < 4; ++m) {
        f32x4 part;
#pragma unroll
        for (int r = 0; r < 4; ++r)
            part[r] = acc[m][0][r] * af0 + acc[m][1][r] * af1;
#pragma unroll
        for (int off = 1; off < 16; off <<= 1)
#pragma unroll
            for (int r = 0; r < 4; ++r) part[r] += __shfl_xor(part[r], off);
        if (l15 == 0)
            *reinterpret_cast<f32x4*>(&Sr[wc * 128 + wr * 64 + m * 16 + q4 * 4]) = part;
    }
    __syncthreads();
    const int t = threadIdx.x;
    if (t < 128) {
        float s = Sr[t] + Sr[128 + t];
        short eb = f2b(expf(s));
        Eb[t] = eb;
        ebT[((size_t)b * H_ + head) * N_ + j0g + t] = eb;
    }
    __syncthreads();
#pragma unroll
    for (int m = 0; m < 4; ++m) {
        int jl = wr * 64 + m * 16 + q4 * 4;
        float ev[4];
#pragma unroll
        for (int r = 0; r < 4; ++r) ev[r] = b2f(Eb[jl + r]);
#pragma unroll
        for (int n = 0; n < 2; ++n) {
            int cl = wc * 32 + n * 16 + l15;
            s16x4 gv;
#pragma unroll
            for (int r = 0; r < 4; ++r) gv[r] = f2b(acc[m][n][r] * ev[r]);
            *reinterpret_cast<s16x4*>(&Tt[cl * 136 + jl]) = gv;
        }
    }
    __syncthreads();
    {
        int c  = t >> 2;
        int jc = (t & 3) * 32;
        short* dst = &gT[((size_t)b * C_ + n0 + c) * N_ + j0g + jc];
#pragma unroll
        for (int u = 0; u < 4; ++u)
            *reinterpret_cast<bf16x8*>(dst + u * 8) =
                *reinterpret_cast<const bf16x8*>(&Tt[c * 136 + jc + u * 8]);
    }
}

// ---------------------------------------------------------------------------
// Kernel 3: numerator GEMM (bf16 MFMA) + denominator + divide.
// 512 threads = 8 waves (4 row x 2 col), wave tile 32x32.
// Double-buffered LDS, prefetch-before-compute (2-phase pipeline).
// A staged DIRECTLY from adj int32: issue-early global loads, convert +
// swizzled ds_write late (after MFMAs). B (gT) + E via global_load_lds.
//   num[i,c] = sum_j adj * gT[b,c,j] ;  den[i] = sum_j adj * e[b,head,j]
//   out = num / den
// ---------------------------------------------------------------------------
__global__ __launch_bounds__(512)
void agg_mfma(const int* __restrict__ adj, const short* __restrict__ gT,
              const short* __restrict__ ebT, float* __restrict__ out) {
    __shared__ short As[2][128 * 64];   // 32 KiB
    __shared__ short Bs[2][64 * 64];    // 16 KiB
    __shared__ short Es[N_];            //  4 KiB
    __shared__ float Dr[128];
    const int b  = blockIdx.z;
    const int m0 = blockIdx.x * 128;
    const int n0 = blockIdx.y * 64;
    const int head = n0 >> 6;
    const int tid  = threadIdx.x;
    const int wid  = tid >> 6;              // 0..7
    const int lane = tid & 63;
    const int wr = wid >> 1, wc = wid & 1;  // 4 x 2 waves
    const int q4 = lane >> 4, l15 = lane & 15;
    const int lr = lane >> 3;
    const int ls = (lane & 7) ^ lr;
    const int ar = tid >> 2;                // A-stage: row 0..127
    const int ap = tid & 3;                 // A-stage: k-part (16 ints)

    const int*   Abase = adj + (size_t)b * N_ * N_ + (size_t)m0 * N_;
    const short* Bbase = gT  + (size_t)b * C_ * N_ + (size_t)n0 * N_;
    const short* Ebase = ebT + ((size_t)b * H_ + head) * N_;

    int4 av[4];

#define STAGE_B(buf, k0s) do {                                                  \
        int row_ = wid * 8 + lr;                                                \
        GL2LDS(Bbase + (size_t)row_ * N_ + (k0s) + ls * 8, &Bs[buf][wid * 512]);\
    } while (0)

#define A_LOAD(k0s) do {                                                        \
        const int* src_ = Abase + (size_t)ar * N_ + (k0s) + ap * 16;            \
        av[0] = *reinterpret_cast<const int4*>(src_);                           \
        av[1] = *reinterpret_cast<const int4*>(src_ + 4);                       \
        av[2] = *reinterpret_cast<const int4*>(src_ + 8);                       \
        av[3] = *reinterpret_cast<const int4*>(src_ + 12);                      \
    } while (0)

#define A_WRITE(buf) do {                                                       \
        bf16x8 w0_, w1_;                                                        \
        w0_[0] = av[0].x ? (short)0x3F80 : (short)0;                            \
        w0_[1] = av[0].y ? (short)0x3F80 : (short)0;                            \
        w0_[2] = av[0].z ? (short)0x3F80 : (short)0;                            \
        w0_[3] = av[0].w ? (short)0x3F80 : (short)0;                            \
        w0_[4] = av[1].x ? (short)0x3F80 : (short)0;                            \
        w0_[5] = av[1].y ? (short)0x3F80 : (short)0;                            \
        w0_[6] = av[1].z ? (short)0x3F80 : (short)0;                            \
        w0_[7] = av[1].w ? (short)0x3F80 : (short)0;                            \
        w1_[0] = av[2].x ? (short)0x3F80 : (short)0;                            \
        w1_[1] = av[2].y ? (short)0x3F80 : (short)0;                            \
        w1_[2] = av[2].z ? (short)0x3F80 : (short)0;                            \
        w1_[3] = av[2].w ? (short)0x3F80 : (short)0;                            \
        w1_[4] = av[3].x ? (short)0x3F80 : (short)0;                            \
        w1_[5] = av[3].y ? (short)0x3F80 : (short)0;                            \
        w1_[6] = av[3].z ? (short)0x3F80 : (short)0;                            \
        w1_[7] = av[3].w ? (short)0x3F80 : (short)0;                            \
        int g0_ = (ap * 2)     ^ (ar & 7);                                      \
        int g1_ = (ap * 2 + 1) ^ (ar & 7);                                      \
        *reinterpret_cast<bf16x8*>(&As[buf][ar * 64 + g0_ * 8]) = w0_;          \
        *reinterpret_cast<bf16x8*>(&As[buf][ar * 64 + g1_ * 8]) = w1_;          \
    } while (0)

    f32x4 acc[2][2];
    f32x4 accd = (f32x4){0.f, 0.f, 0.f, 0.f};
#pragma unroll
    for (int m = 0; m < 2; ++m)
#pragma unroll
        for (int n = 0; n < 2; ++n) acc[m][n] = (f32x4){0.f, 0.f, 0.f, 0.f};

    // prologue: E + tile 0
    if (wid < 4) GL2LDS(Ebase + wid * 512 + lane * 8, Es + wid * 512);
    STAGE_B(0, 0);
    A_LOAD(0);
    A_WRITE(0);
    __syncthreads();

#pragma unroll 2
    for (int t = 0; t < 32; ++t) {
        const int buf = t & 1;
        const int k0  = t * 64;
        if (t < 31) {                    // prefetch next tile (issue-early)
            STAGE_B(buf ^ 1, k0 + 64);
            A_LOAD(k0 + 64);
        }
        // compute current tile
#pragma unroll
        for (int kk = 0; kk < 2; ++kk) {
            const int gA = kk * 4 + q4;
            bf16x8 a[2], bb[2], be;
#pragma unroll
            for (int m = 0; m < 2; ++m) {
                int row = wr * 32 + m * 16 + l15;
                a[m] = *reinterpret_cast<const bf16x8*>(&As[buf][row * 64 + (gA ^ (row & 7)) * 8]);
            }
#pragma unroll
            for (int n = 0; n < 2; ++n) {
                int row = wc * 32 + n * 16 + l15;
                bb[n] = *reinterpret_cast<const bf16x8*>(&Bs[buf][row * 64 + (gA ^ (row & 7)) * 8]);
            }
            be = *reinterpret_cast<const bf16x8*>(&Es[k0 + kk * 32 + q4 * 8]);
#pragma unroll
            for (int m = 0; m < 2; ++m)
#pragma unroll
                for (int n = 0; n < 2; ++n)
                    acc[m][n] = __builtin_amdgcn_mfma_f32_16x16x32_bf16(a[m], bb[n], acc[m][n], 0, 0, 0);
            // balanced den: wave (wr,wc) covers rows wr*32 + wc*16 + 0..15
            accd = __builtin_amdgcn_mfma_f32_16x16x32_bf16(wc ? a[1] : a[0], be, accd, 0, 0, 0);
        }
        if (t < 31) A_WRITE(buf ^ 1);    // write-late (loads drained here)
        __syncthreads();
    }

    // den -> LDS (col 0 lanes hold rows q4*4..q4*4+3 of this wave's 16-row slab)
    if (l15 == 0)
        *reinterpret_cast<f32x4*>(&Dr[wr * 32 + wc * 16 + q4 * 4]) = accd;
    __syncthreads();

    float* obase = out + (size_t)b * N_ * C_;
#pragma unroll
    for (int m = 0; m < 2; ++m) {
        int jl = wr * 32 + m * 16 + q4 * 4;
        float inv[4];
#pragma unroll
        for (int r = 0; r < 4; ++r) inv[r] = 1.0f / Dr[jl + r];
#pragma unroll
        for (int n = 0; n < 2; ++n) {
            int gc = n0 + wc * 32 + n * 16 + l15;
#pragma unroll
            for (int r = 0; r < 4; ++r)
                obase[(size_t)(m0 + jl + r) * C_ + gc] = acc[m][n][r] * inv[r];
        }
    }
#undef STAGE_B
#undef A_LOAD
#undef A_WRITE
}

// ---------------------------------------------------------------------------
extern "C" void kernel_launch(void* const* d_in, const int* in_sizes, int n_in,
                              void* d_out, int out_size, void* d_ws, size_t ws_size,
                              hipStream_t stream) {
    const float* x        = (const float*)d_in[0];
    const int*   adj      = (const int*)d_in[1];
    const float* weight   = (const float*)d_in[2];
    // d_in[3] = attn_src : unused (cancels in softmax over neighbors j)
    const float* attn_dst = (const float*)d_in[4];
    float* out = (float*)d_out;

    // workspace:
    //   xb  : 4 MiB bf16
    //   wbT : 256 KiB bf16
    //   ebT : 128 KiB bf16   [b][h][j]
    //   gT  : 8 MiB bf16     [b][c][j]
    short* xb  = (short*)d_ws;
    short* wbT = xb + (size_t)B_ * N_ * INF_;
    short* ebT = wbT + (size_t)C_ * INF_;
    short* gT  = ebT + (size_t)B_ * H_ * N_;

    // 1. casts: x->xb, W->wbT
    cast_kernel<<<dim3(1024 + 32), 256, 0, stream>>>(x, weight, xb, wbT);
    // 2. fused projection + e + gT
    proj_fused<<<dim3((B_ * N_) / 128, C_ / 64), 256, 0, stream>>>(xb, wbT, attn_dst, ebT, gT);
    // 3. numerator GEMM + denominator (MFMA) + divide -> out  (reads adj directly)
    agg_mfma<<<dim3(N_ / 128, C_ / 64, B_), 512, 0, stream>>>(adj, gT, ebT, out);
}